// Round 6
// baseline (215.740 us; speedup 1.0000x reference)
//
#include <hip/hip_runtime.h>
#include <hip/hip_bf16.h>

#define Bn   8
#define Cn   64
#define Nn   40962
#define Kn   7
#define OUTn 64
#define NVT32  1281   // 32-vertex tiles per batch
#define GROUPS 128    // persistent groups per batch
// flattened K dim = Kn*Cn = 448 = 14 chunks of 32

typedef __bf16 bf16x8 __attribute__((ext_vector_type(8)));
typedef __bf16 bf16x4 __attribute__((ext_vector_type(4)));
typedef float  f32x4  __attribute__((ext_vector_type(4)));

// ---------------------------------------------------------------------------
// Pass 1: transpose+convert x [B, C, N] f32 -> xT [B, N, C] bf16.
// (held constant -- ~33 us vs 20 us traffic floor; not this round's lever)
// ---------------------------------------------------------------------------
__global__ __launch_bounds__(256) void transpose_kernel(
    const float* __restrict__ x, __bf16* __restrict__ xT,
    const float* __restrict__ W, __bf16* __restrict__ Wb, int b0)
{
    __shared__ unsigned int tile[64][65];   // [c][n-pair slot]; +1 pad
    const int tid  = threadIdx.x;
    const int lane = tid & 63;
    const int w    = tid >> 6;
    const int n0   = blockIdx.x * 128;
    const int bl   = blockIdx.y;
    const int b    = b0 + bl;
    const size_t xb = (size_t)b * Cn * Nn;

    // fused convw: first 112 blocks of bl==0 slice cover 28672 W elements
    if (bl == 0) {
        const int wi = blockIdx.x * 256 + tid;
        if (wi < OUTn * Kn * Cn) Wb[wi] = (__bf16)W[wi];
    }

    const int n = n0 + lane * 2;
    if (n < Nn) {
#pragma unroll
        for (int i = 0; i < 16; ++i) {
            const int c = w * 16 + i;
            const float2 v = *(const float2*)(x + xb + (size_t)c * Nn + n);
            const unsigned short ua =
                __builtin_bit_cast(unsigned short, (__bf16)v.x);
            const unsigned short ub =
                __builtin_bit_cast(unsigned short, (__bf16)v.y);
            tile[c][lane] = ((unsigned)ub << 16) | (unsigned)ua;
        }
    }
    __syncthreads();

    const int rsub = lane >> 3;
    const int cblk = lane & 7;
#pragma unroll
    for (int it = 0; it < 4; ++it) {
        const int row = it * 32 + w * 8 + rsub;
        const int n1  = n0 + row;
        if (n1 < Nn) {
            const int slot = row >> 1;
            const int sh   = (row & 1) * 16;
            bf16x8 frag;
#pragma unroll
            for (int e = 0; e < 8; ++e) {
                const unsigned u = tile[cblk * 8 + e][slot];
                frag[e] = __builtin_bit_cast(
                    __bf16, (unsigned short)((u >> sh) & 0xffffu));
            }
            *(bf16x8*)(xT + ((size_t)bl * Nn + n1) * Cn + cblk * 8) = frag;
        }
    }
}

// ---------------------------------------------------------------------------
// Pass 2 v7: persistent-block gather-GEMM with tile-level DOUBLE-BUFFER and
// counted vmcnt (T3/T4 proper).
// A/B ledger: per-stage barriers depth1 vs depth3 (80.7->77.3, null);
// all-at-once stage + 2 barriers/tile (77.3->56.5, REAL); ds_read halving
// (56.5->56.3, null). Only drain-exposure reduction has ever helped =>
// remove the drain from the critical path entirely:
//   iter t: s_barrier (WAR on buf[p^1]) -> STAGE tile t+1 into buf[p^1]
//           (7 fire-and-forget global_load_lds/wave) -> vmcnt(7) ->
//           s_barrier -> compute tile t from buf[p].
// The vmcnt(7) waits on loads issued ONE FULL ITERATION (~1500+ cy) ago;
// no vmcnt(0) anywhere in the loop. Count robustness: the 7 newest VMEM
// are exactly STAGE(t+1), fenced by sched_barrier(0) both sides; all other
// VMEM (idx loads, epilogue stores) is strictly older, so vmcnt(7) proves
// tile-t complete regardless of compiler emission counts.
// Safety: own-vmcnt-then-s_barrier => all waves' tile-t rows visible
// (round-2 argument); WAR barrier precedes restage; compute's ds_reads
// retired before the wave reaches the next WAR barrier (data consumed by
// MFMAs under compiler lgkmcnt waits).
// Tile 64->32 vertices so TWO buffers fit 2 blocks/CU (2 x 28.7 KB).
// Wave w = (wv=w&1 vertex half, wo=w>>1 output pair); stages rows
// [8w,8w+8); one gll per kn. XOR chunk scheme unchanged (slot = q^(col&7),
// conflict-free, SQ_LDS_BANK_CONFLICT==0 rounds 1-5). blk&7 = batch = XCD.
// Last iteration stages one speculative clamped tile (~29 MB extra L2
// traffic total) -- accepted for count-stable waits.
// ---------------------------------------------------------------------------
__global__ __launch_bounds__(256, 2) void gconv_kernel(
    const __bf16* __restrict__ xT,    // [B, N, C] bf16
    const int*    __restrict__ nbr,   // [N*7] int32
    const __bf16* __restrict__ Wb,    // [64, 448] bf16
    const float*  __restrict__ bias,  // [64] f32
    float*        __restrict__ out)   // [B, 64, N] f32
{
    __shared__ __bf16 sbuf[2][Kn][32][64];   // 2 x 28672 B

    const int blk  = blockIdx.x;
    const int bl   = blk & 7;         // batch == XCD
    const int grp  = blk >> 3;        // 0..127 within batch
    const int w    = threadIdx.x >> 6;
    const int l    = threadIdx.x & 63;
    const int col  = l & 15;
    const int quad = l >> 4;
    const int rme  = l >> 3;          // row within this wave's 8-row stripe
    const int srcoff = ((l & 7) ^ rme) * 16;   // chunk-permuted source
    const int wv   = w & 1;           // vertex half (16 vertices)
    const int wo   = w >> 1;          // output pair (s in {2wo, 2wo+1})
    const __bf16* xb = xT + (size_t)bl * Nn * Cn;

    // ---- A fragments: W rows (2wo+s)*16+col, all 14 k-chunks, once ----
    bf16x8 aW[2][14];
#pragma unroll
    for (int s = 0; s < 2; ++s)
#pragma unroll
        for (int kc = 0; kc < 14; ++kc)
            aW[s][kc] = *(const bf16x8*)(Wb
                + (size_t)((wo * 2 + s) * 16 + col) * (Kn * Cn)
                + kc * 32 + quad * 8);

    float bv[2][4];
#pragma unroll
    for (int s = 0; s < 2; ++s)
#pragma unroll
        for (int r4 = 0; r4 < 4; ++r4)
            bv[s][r4] = bias[(wo * 2 + s) * 16 + quad * 4 + r4];

    // offsets for the ONE row this lane stages (row = w*8 + rme of the tile)
#define LOADIDX(vt_, dst_)                                                    \
    {                                                                         \
        int v = (vt_)*32 + w * 8 + rme;                                       \
        if (v > Nn - 1) v = Nn - 1;                                           \
        _Pragma("unroll")                                                     \
        for (int kn = 0; kn < Kn; ++kn) {                                     \
            int id = nbr[v * 7 + kn];                                         \
            id = id < 0 ? 0 : (id >= Nn ? Nn - 1 : id);                       \
            dst_[kn] = id * (Cn * 2);                                         \
        }                                                                     \
    }

#define STAGE(p_, ofs_)                                                       \
    {                                                                         \
        _Pragma("unroll")                                                     \
        for (int kn = 0; kn < Kn; ++kn) {                                     \
            const char* src_ = (const char*)xb + ofs_[kn] + srcoff;           \
            __builtin_amdgcn_global_load_lds(                                 \
                (const unsigned int*)src_,                                    \
                (unsigned int*)&sbuf[p_][kn][w * 8][0], 16, 0, 0);            \
        }                                                                     \
    }

    // ---- prologue: stage tile0, prefetch tile1's offsets ----
    int ofsC[Kn];
    LOADIDX(grp, ofsC)
    __builtin_amdgcn_sched_barrier(0);
    STAGE(0, ofsC)
    __builtin_amdgcn_sched_barrier(0);
    LOADIDX(grp + GROUPS, ofsC)

    int p = 0;
    for (int vt = grp; vt < NVT32; vt += GROUPS) {
        __builtin_amdgcn_s_barrier();      // WAR: all waves done reading buf[p^1]
        __builtin_amdgcn_sched_barrier(0);
        STAGE(p ^ 1, ofsC)                 // tile t+1 (clamped past end: wasted)
        __builtin_amdgcn_sched_barrier(0);
        asm volatile("s_waitcnt vmcnt(7)" ::: "memory");   // tile t landed
        __builtin_amdgcn_s_barrier();      // all waves' tile-t rows visible
        __builtin_amdgcn_sched_barrier(0);

        LOADIDX(vt + 2 * GROUPS, ofsC)     // tile t+2 offsets, under compute

        // ---- compute: 14 ds_read_b128 + 28 MFMA per wave ----
        f32x4 acc[2];
        acc[0] = (f32x4){0.f, 0.f, 0.f, 0.f};
        acc[1] = (f32x4){0.f, 0.f, 0.f, 0.f};

        __builtin_amdgcn_s_setprio(1);
#pragma unroll
        for (int kn = 0; kn < Kn; ++kn) {
#pragma unroll
            for (int h = 0; h < 2; ++h) {
                const int q    = h * 4 + quad;
                const int slot = q ^ (col & 7);
                const bf16x8 bf =
                    *(const bf16x8*)&sbuf[p][kn][wv * 16 + col][slot * 8];
#pragma unroll
                for (int s = 0; s < 2; ++s)
                    acc[s] = __builtin_amdgcn_mfma_f32_16x16x32_bf16(
                        aW[s][kn * 2 + h], bf, acc[s], 0, 0, 0);
            }
        }
        __builtin_amdgcn_s_setprio(0);

        // ---- epilogue: col -> vertex, quad*4+r4 -> o ----
        const int n = vt * 32 + wv * 16 + col;
        if (n < Nn) {
#pragma unroll
            for (int s = 0; s < 2; ++s)
#pragma unroll
                for (int r4 = 0; r4 < 4; ++r4) {
                    const int o = (wo * 2 + s) * 16 + quad * 4 + r4;
                    out[((size_t)bl * OUTn + o) * Nn + n] =
                        acc[s][r4] + bv[s][r4];
                }
        }
        p ^= 1;
    }
#undef LOADIDX
#undef STAGE
}

// ---------------------------------------------------------------------------
// Fallback: no workspace needed. Pure f32. Slow but correct.
// ---------------------------------------------------------------------------
__global__ __launch_bounds__(256) void naive_kernel(
    const float* __restrict__ x, const int* __restrict__ nbr,
    const float* __restrict__ W, const float* __restrict__ bias,
    float* __restrict__ out)
{
    __shared__ float xs[4][Kn * Cn];
    const int v = threadIdx.x >> 6;
    const int o = threadIdx.x & 63;
    const int b = blockIdx.y;
    const int n = blockIdx.x * 4 + v;
    const bool ok = n < Nn;
    const int nn = ok ? n : 0;

#pragma unroll
    for (int k = 0; k < Kn; ++k) {
        int id = nbr[nn * Kn + k];
        id = id < 0 ? 0 : (id >= Nn ? Nn - 1 : id);
        xs[v][k * Cn + o] = x[((size_t)b * Cn + o) * Nn + id];
    }
    __syncthreads();

    float acc = bias[o];
    for (int j = 0; j < Kn * Cn; ++j)
        acc += W[o * (Kn * Cn) + j] * xs[v][j];

    if (ok)
        out[((size_t)b * OUTn + o) * Nn + n] = acc;
}

extern "C" void kernel_launch(void* const* d_in, const int* in_sizes, int n_in,
                              void* d_out, int out_size, void* d_ws, size_t ws_size,
                              hipStream_t stream)
{
    const float* x    = (const float*)d_in[0];
    const int*   nbr  = (const int*)d_in[1];
    const float* W    = (const float*)d_in[2];
    const float* bias = (const float*)d_in[3];
    float*       out  = (float*)d_out;

    const size_t w_bytes     = (size_t)OUTn * Kn * Cn * sizeof(__bf16); // 57344
    const size_t batch_bytes = (size_t)Nn * Cn * sizeof(__bf16);        // 5.24 MB
    int nb = 0;
    if (ws_size > w_bytes)
        nb = (int)((ws_size - w_bytes) / batch_bytes);
    if (nb > Bn) nb = Bn;

    if (nb >= Bn) {
        __bf16* Wb = (__bf16*)d_ws;
        __bf16* xT = (__bf16*)((char*)d_ws + w_bytes);

        dim3 tgrid((Nn + 127) / 128, Bn);
        transpose_kernel<<<tgrid, 256, 0, stream>>>(x, xT, W, Wb, 0);
        gconv_kernel<<<Bn * GROUPS, 256, 0, stream>>>(xT, nbr, Wb, bias, out);
    } else {
        dim3 ngrid((Nn + 3) / 4, Bn);
        naive_kernel<<<ngrid, 256, 0, stream>>>(x, nbr, W, bias, out);
    }
}